// Round 3
// baseline (1787.463 us; speedup 1.0000x reference)
//
#include <hip/hip_runtime.h>
#include <hip/hip_bf16.h>
#include <math.h>

#define B_ 4
#define T_ 1024
#define D_ 1024
#define H_ 16
#define DH_ 64
#define F_ 4096
#define E_ 8
#define NTOK 4096
#define EPS_ 1e-5f

typedef float f32x4 __attribute__((ext_vector_type(4)));
typedef __bf16 bf16x8 __attribute__((ext_vector_type(8)));

__device__ __forceinline__ unsigned short f2bf(float f) {
    unsigned u = __float_as_uint(f);
    u = u + 0x7fffu + ((u >> 16) & 1u);   // round-to-nearest-even
    return (unsigned short)(u >> 16);
}

__device__ __forceinline__ void blockreduce2(float& s, float& sq) {
    #pragma unroll
    for (int o = 32; o > 0; o >>= 1) { s += __shfl_xor(s, o); sq += __shfl_xor(sq, o); }
    __shared__ float ls[4], lq[4];
    int w = threadIdx.x >> 6;
    if ((threadIdx.x & 63) == 0) { ls[w] = s; lq[w] = sq; }
    __syncthreads();
    s = ls[0] + ls[1] + ls[2] + ls[3];
    sq = lq[0] + lq[1] + lq[2] + lq[3];
}

// ---------------- zero routing counters ----------------
__global__ void k_zero(int* __restrict__ cnt) {
    if (threadIdx.x < E_) cnt[threadIdx.x] = 0;
}

// ------------- transpose fp32[e][R][C] -> bf16[e][C][R] -------------
__global__ void k_tconv(const float* __restrict__ in, unsigned short* __restrict__ out,
                        int R, int C) {
    __shared__ float tile[32][33];
    int e = blockIdx.z;
    const float* ine = in + (size_t)e * R * C;
    unsigned short* oute = out + (size_t)e * R * C;
    int tx = threadIdx.x & 31, ty = threadIdx.x >> 5;   // 32 x 8
    int c0 = blockIdx.x * 32, r0 = blockIdx.y * 32;
    #pragma unroll
    for (int j = 0; j < 32; j += 8)
        tile[ty + j][tx] = ine[(size_t)(r0 + ty + j) * C + c0 + tx];
    __syncthreads();
    #pragma unroll
    for (int j = 0; j < 32; j += 8)
        oute[(size_t)(c0 + ty + j) * R + r0 + tx] = f2bf(tile[tx][ty + j]);
}

// ---------------- LayerNorm (fp32 out) ----------------
__global__ void k_ln1(const float* __restrict__ x, const float* __restrict__ g,
                      const float* __restrict__ b, float* __restrict__ h) {
    int row = blockIdx.x, t = threadIdx.x;
    f32x4 v = *(const f32x4*)(x + (size_t)row * D_ + t * 4);
    float s = v.x + v.y + v.z + v.w;
    float sq = v.x * v.x + v.y * v.y + v.z * v.z + v.w * v.w;
    blockreduce2(s, sq);
    float mean = s * (1.0f / D_);
    float var = sq * (1.0f / D_) - mean * mean;
    float inv = rsqrtf(var + EPS_);
    f32x4 gv = *(const f32x4*)(g + t * 4);
    f32x4 bv = *(const f32x4*)(b + t * 4);
    f32x4 o;
    o.x = (v.x - mean) * inv * gv.x + bv.x;
    o.y = (v.y - mean) * inv * gv.y + bv.y;
    o.z = (v.z - mean) * inv * gv.z + bv.z;
    o.w = (v.w - mean) * inv * gv.w + bv.w;
    *(f32x4*)(h + (size_t)row * D_ + t * 4) = o;
}

// ---------------- fp32 128x128 GEMM core (BK=8, 8x8 per thread) ----------------
#define FBK 8
__device__ __forceinline__ void gemm128_f32(const float* __restrict__ A,
        const float* __restrict__ W, int m0, int n0, int K, int N, float acc[8][8]) {
    __shared__ float As[FBK][128];
    __shared__ float Bs[FBK][128];
    int t = threadIdx.x;
    int tx = t & 15, ty = t >> 4;
    int arow = t >> 1, akc = (t & 1) * 4;
    int bk = t >> 5, bcol = (t & 31) * 4;
    const float* Ap = A + (size_t)(m0 + arow) * K + akc;
    const float* Wp = W + (size_t)bk * N + n0 + bcol;
    for (int k0 = 0; k0 < K; k0 += FBK) {
        f32x4 av = *(const f32x4*)(Ap + k0);
        f32x4 bv = *(const f32x4*)(Wp + (size_t)k0 * N);
        __syncthreads();
        As[akc + 0][arow] = av.x; As[akc + 1][arow] = av.y;
        As[akc + 2][arow] = av.z; As[akc + 3][arow] = av.w;
        *(f32x4*)(&Bs[bk][bcol]) = bv;
        __syncthreads();
        #pragma unroll
        for (int kk = 0; kk < FBK; kk++) {
            f32x4 a0 = *(const f32x4*)(&As[kk][ty * 8]);
            f32x4 a1 = *(const f32x4*)(&As[kk][ty * 8 + 4]);
            f32x4 b0 = *(const f32x4*)(&Bs[kk][tx * 8]);
            f32x4 b1 = *(const f32x4*)(&Bs[kk][tx * 8 + 4]);
            float aa[8] = {a0.x, a0.y, a0.z, a0.w, a1.x, a1.y, a1.z, a1.w};
            float bb[8] = {b0.x, b0.y, b0.z, b0.w, b1.x, b1.y, b1.z, b1.w};
            #pragma unroll
            for (int i = 0; i < 8; i++)
                #pragma unroll
                for (int j = 0; j < 8; j++)
                    acc[i][j] = fmaf(aa[i], bb[j], acc[i][j]);
        }
    }
}

// ---------------- QKV projection (fp32), scatter to [B,H,T,DH] ----------------
__global__ __launch_bounds__(256, 2) void k_qkv(const float* __restrict__ h1,
        const float* __restrict__ wq, const float* __restrict__ wk, const float* __restrict__ wv,
        const float* __restrict__ bq, const float* __restrict__ bk, const float* __restrict__ bv,
        float* __restrict__ Q, float* __restrict__ Kk, float* __restrict__ V) {
    int which = blockIdx.z;
    const float* W = (which == 0) ? wq : ((which == 1) ? wk : wv);
    const float* bias = (which == 0) ? bq : ((which == 1) ? bk : bv);
    float* O = (which == 0) ? Q : ((which == 1) ? Kk : V);
    float acc[8][8];
    #pragma unroll
    for (int i = 0; i < 8; i++)
        #pragma unroll
        for (int j = 0; j < 8; j++) acc[i][j] = 0.f;
    int m0 = blockIdx.y * 128, n0 = blockIdx.x * 128;
    gemm128_f32(h1, W, m0, n0, D_, D_, acc);
    int t = threadIdx.x, tx = t & 15, ty = t >> 4;
    #pragma unroll
    for (int i = 0; i < 8; i++) {
        int m = m0 + ty * 8 + i;
        int bidx = m >> 10, tt = m & 1023;
        #pragma unroll
        for (int jj = 0; jj < 8; jj += 4) {
            int n = n0 + tx * 8 + jj;
            int hh = n >> 6, d = n & 63;
            f32x4 o;
            o.x = acc[i][jj + 0] + bias[n + 0];
            o.y = acc[i][jj + 1] + bias[n + 1];
            o.z = acc[i][jj + 2] + bias[n + 2];
            o.w = acc[i][jj + 3] + bias[n + 3];
            *(f32x4*)(O + (((size_t)bidx * H_ + hh) * T_ + tt) * DH_ + d) = o;
        }
    }
}

// ---------------- output projection + residual (fp32) ----------------
__global__ __launch_bounds__(256, 2) void k_proj(const float* __restrict__ att,
        const float* __restrict__ wo, const float* __restrict__ bo,
        const float* __restrict__ x, float* __restrict__ x2) {
    float acc[8][8];
    #pragma unroll
    for (int i = 0; i < 8; i++)
        #pragma unroll
        for (int j = 0; j < 8; j++) acc[i][j] = 0.f;
    int m0 = blockIdx.y * 128, n0 = blockIdx.x * 128;
    gemm128_f32(att, wo, m0, n0, D_, D_, acc);
    int t = threadIdx.x, tx = t & 15, ty = t >> 4;
    #pragma unroll
    for (int i = 0; i < 8; i++) {
        int m = m0 + ty * 8 + i;
        #pragma unroll
        for (int jj = 0; jj < 8; jj += 4) {
            int n = n0 + tx * 8 + jj;
            f32x4 xv = *(const f32x4*)(x + (size_t)m * D_ + n);
            f32x4 o;
            o.x = acc[i][jj + 0] + bo[n + 0] + xv.x;
            o.y = acc[i][jj + 1] + bo[n + 1] + xv.y;
            o.z = acc[i][jj + 2] + bo[n + 2] + xv.z;
            o.w = acc[i][jj + 3] + bo[n + 3] + xv.w;
            *(f32x4*)(x2 + (size_t)m * D_ + n) = o;
        }
    }
}

// ---------------- flash attention pass 1: uniform split-K partials ----------------
// grid (sp=4, qt=16, bh=64). Block = 4 waves; block owns <=256 keys of one
// 64-query tile. Wave-private LDS staging (no in-loop syncthreads). Partial
// (m, l, unnormalized o) merged in-block, written to compacted slots.
#define NSLOT 40
__device__ __forceinline__ int slot_base(int qt) {
    const int base[16] = {0,1,2,3,4,6,8,10,12,15,18,21,24,28,32,36};
    return base[qt];
}
__global__ __launch_bounds__(256) void k_attn1(const float* __restrict__ Q,
        const float* __restrict__ K, const float* __restrict__ V,
        float* __restrict__ opart, float* __restrict__ mlpart) {
    __shared__ float S[4 * 2 * 16 * 64];     // 4 waves x (K 16x64 + V 16x64); reused as merge buf
    __shared__ float Ml[4][64][2];
    int sp = blockIdx.x, qt = blockIdx.y, bh = blockIdx.z;
    int lim = (qt + 1) * 64;
    int s0 = sp * 256;
    if (s0 >= lim) return;
    int span = min(256, lim - s0);
    int nch = span >> 4;                      // 16-key chunks: 4/8/12/16, divisible by 4
    int tid = threadIdx.x;
    int w = tid >> 6, lane = tid & 63;
    const float* Qb = Q + (size_t)bh * T_ * DH_;
    const float* Kb = K + (size_t)bh * T_ * DH_;
    const float* Vb = V + (size_t)bh * T_ * DH_;
    int qrow = qt * 64 + lane;
    float* Kw = S + w * (2 * 16 * 64);
    float* Vw = Kw + 16 * 64;
    f32x4 q[16], o[16];
    #pragma unroll
    for (int i = 0; i < 16; i++) {
        q[i] = *(const f32x4*)(Qb + (size_t)qrow * DH_ + i * 4);
        o[i].x = 0.f; o[i].y = 0.f; o[i].z = 0.f; o[i].w = 0.f;
    }
    float m = -1e30f, l = 0.f;
    int c4 = lane * 4;
    for (int c = w; c < nch; c += 4) {
        int kbase = s0 + c * 16;
        // flat staging (R0 pattern: measured 0 bank conflicts)
        #pragma unroll
        for (int i = 0; i < 4; i++) {
            int fl = i * 256 + c4;
            *(f32x4*)(Kw + fl) = *(const f32x4*)(Kb + (size_t)kbase * DH_ + fl);
            *(f32x4*)(Vw + fl) = *(const f32x4*)(Vb + (size_t)kbase * DH_ + fl);
        }
        __builtin_amdgcn_s_waitcnt(0);   // lgkmcnt(0): own-wave LDS writes visible
        float s[16];
        float cmax = -1e30f;
        #pragma unroll
        for (int j = 0; j < 16; j++) {
            f32x4 a4 = {0.f, 0.f, 0.f, 0.f};
            #pragma unroll
            for (int i = 0; i < 16; i++) {
                f32x4 kv = *(const f32x4*)(&Kw[j * 64 + i * 4]);   // broadcast read
                a4 += q[i] * kv;
            }
            float sv = (a4.x + a4.y + a4.z + a4.w) * 0.125f;
            sv = (kbase + j <= qrow) ? sv : -1e30f;
            s[j] = sv;
            cmax = fmaxf(cmax, sv);
        }
        float mnew = fmaxf(m, cmax);
        float alpha = __expf(m - mnew);
        l *= alpha;
        #pragma unroll
        for (int i = 0; i < 16; i++) o[i] *= alpha;
        m = mnew;
        #pragma unroll
        for (int j = 0; j < 16; j++) {
            // fully-masked chunk keeps s=-1e30; exp would be wrong without guard
            float p = (s[j] > -1e29f) ? __expf(s[j] - mnew) : 0.f;
            l += p;
            #pragma unroll
            for (int i = 0; i < 16; i++) {
                f32x4 vv = *(const f32x4*)(&Vw[j * 64 + i * 4]);   // broadcast read
                o[i] += p * vv;
            }
        }
    }
    // ---- merge 4 per-wave partial states (some waves may be all-masked: m=-1e30,l=0) ----
    __syncthreads();
    Ml[w][lane][0] = m; Ml[w][lane][1] = l;
    __syncthreads();
    float mt = -1e30f;
    #pragma unroll
    for (int ww = 0; ww < 4; ww++) mt = fmaxf(mt, Ml[ww][lane][0]);
    float scale = __expf(m - mt);            // -1e30 - mt -> exp ~ 0
    #pragma unroll
    for (int i = 0; i < 16; i++) o[i] *= scale;
    float* Om = S;                            // reuse staging LDS; stride 68 keeps 16B align
    if (w == 0) {
        #pragma unroll
        for (int i = 0; i < 16; i++) *(f32x4*)(Om + lane * 68 + i * 4) = o[i];
    }
    __syncthreads();
    #pragma unroll
    for (int ww = 1; ww < 4; ww++) {
        if (w == ww) {
            #pragma unroll
            for (int i = 0; i < 16; i++) {
                f32x4 cur = *(f32x4*)(Om + lane * 68 + i * 4);
                *(f32x4*)(Om + lane * 68 + i * 4) = cur + o[i];
            }
        }
        __syncthreads();
    }
    // ---- write unnormalized partial: 256 threads cover 64 q x 64 d ----
    int slot = bh * NSLOT + slot_base(qt) + sp;
    int qr = tid >> 2, c0 = (tid & 3) * 16;
    float mtq = -1e30f;
    #pragma unroll
    for (int ww = 0; ww < 4; ww++) mtq = fmaxf(mtq, Ml[ww][qr][0]);
    float ltq = 0.f;
    #pragma unroll
    for (int ww = 0; ww < 4; ww++) ltq += Ml[ww][qr][1] * __expf(Ml[ww][qr][0] - mtq);
    float* dst = opart + ((size_t)slot * 64 + qr) * 64 + c0;
    #pragma unroll
    for (int i = 0; i < 4; i++)
        *(f32x4*)(dst + i * 4) = *(const f32x4*)(Om + qr * 68 + c0 + i * 4);
    if ((tid & 3) == 0) {
        mlpart[slot * 128 + qr * 2 + 0] = mtq;
        mlpart[slot * 128 + qr * 2 + 1] = ltq;
    }
}

// ---------------- flash attention pass 2: merge <=4 partials, normalize ----------------
__global__ void k_attn2(const float* __restrict__ opart, const float* __restrict__ mlpart,
                        float* __restrict__ O) {
    int qt = blockIdx.x, bh = blockIdx.y;
    int b = bh >> 4, h = bh & 15;
    int nsp = (qt >> 2) + 1;
    int slot0 = bh * NSLOT + slot_base(qt);
    int tid = threadIdx.x;
    int q = tid >> 2, d0 = (tid & 3) * 16;
    float ms[4], ls[4];
    float mx = -1e30f;
    for (int s = 0; s < nsp; s++) {
        ms[s] = mlpart[(slot0 + s) * 128 + q * 2 + 0];
        ls[s] = mlpart[(slot0 + s) * 128 + q * 2 + 1];
        mx = fmaxf(mx, ms[s]);
    }
    float den = 0.f;
    f32x4 num[4];
    #pragma unroll
    for (int i = 0; i < 4; i++) { num[i].x = 0.f; num[i].y = 0.f; num[i].z = 0.f; num[i].w = 0.f; }
    for (int s = 0; s < nsp; s++) {
        float sc = __expf(ms[s] - mx);
        den += ls[s] * sc;
        const float* src = opart + ((size_t)(slot0 + s) * 64 + q) * 64 + d0;
        #pragma unroll
        for (int i = 0; i < 4; i++) num[i] += sc * *(const f32x4*)(src + i * 4);
    }
    float inv = 1.0f / den;
    float* Or = O + ((size_t)(b * T_ + qt * 64 + q)) * D_ + h * DH_ + d0;
    #pragma unroll
    for (int i = 0; i < 4; i++) *(f32x4*)(Or + i * 4) = num[i] * inv;
}

// ---------------- LN2 + gate (fp32 logits, top-2, routing) ----------------
__global__ void k_ln2_gate(const float* __restrict__ x2, const float* __restrict__ g,
        const float* __restrict__ bb, const float* __restrict__ gw, const float* __restrict__ gb,
        unsigned short* __restrict__ h2, int* __restrict__ cnt, int* __restrict__ lst,
        int* __restrict__ te, int* __restrict__ ts, float* __restrict__ tp) {
    int row = blockIdx.x, t = threadIdx.x;
    f32x4 v = *(const f32x4*)(x2 + (size_t)row * D_ + t * 4);
    float s = v.x + v.y + v.z + v.w;
    float sq = v.x * v.x + v.y * v.y + v.z * v.z + v.w * v.w;
    blockreduce2(s, sq);
    float mean = s * (1.0f / D_), var = sq * (1.0f / D_) - mean * mean;
    float inv = rsqrtf(var + EPS_);
    f32x4 gv = *(const f32x4*)(g + t * 4);
    f32x4 bv = *(const f32x4*)(bb + t * 4);
    float hv[4];
    #pragma unroll
    for (int i = 0; i < 4; i++) hv[i] = (v[i] - mean) * inv * gv[i] + bv[i];
    ushort4 hb;
    hb.x = f2bf(hv[0]); hb.y = f2bf(hv[1]); hb.z = f2bf(hv[2]); hb.w = f2bf(hv[3]);
    *(ushort4*)(&h2[(size_t)row * D_ + t * 4]) = hb;
    float lg[8];
    #pragma unroll
    for (int e2 = 0; e2 < 8; e2++) lg[e2] = 0.f;
    #pragma unroll
    for (int i = 0; i < 4; i++) {
        const float* gr = gw + (size_t)(t * 4 + i) * E_;
        f32x4 g0 = *(const f32x4*)(gr);
        f32x4 g1 = *(const f32x4*)(gr + 4);
        lg[0] = fmaf(hv[i], g0.x, lg[0]); lg[1] = fmaf(hv[i], g0.y, lg[1]);
        lg[2] = fmaf(hv[i], g0.z, lg[2]); lg[3] = fmaf(hv[i], g0.w, lg[3]);
        lg[4] = fmaf(hv[i], g1.x, lg[4]); lg[5] = fmaf(hv[i], g1.y, lg[5]);
        lg[6] = fmaf(hv[i], g1.z, lg[6]); lg[7] = fmaf(hv[i], g1.w, lg[7]);
    }
    #pragma unroll
    for (int o = 32; o > 0; o >>= 1) {
        #pragma unroll
        for (int e2 = 0; e2 < 8; e2++) lg[e2] += __shfl_xor(lg[e2], o);
    }
    __shared__ float lred[4][8];
    int w = t >> 6;
    if ((t & 63) == 0) {
        #pragma unroll
        for (int e2 = 0; e2 < 8; e2++) lred[w][e2] = lg[e2];
    }
    __syncthreads();
    if (t == 0) {
        float L[8];
        #pragma unroll
        for (int e2 = 0; e2 < 8; e2++)
            L[e2] = (lred[0][e2] + lred[1][e2] + lred[2][e2] + lred[3][e2] + gb[e2]) / 0.9f;
        int e0 = 0, e1 = -1; float v0 = L[0], v1 = -3e38f;
        #pragma unroll
        for (int e2 = 1; e2 < 8; e2++) {
            float xv = L[e2];
            if (xv > v0)      { v1 = v0; e1 = e0; v0 = xv; e0 = e2; }
            else if (xv > v1) { v1 = xv; e1 = e2; }
        }
        float ex = __expf(v1 - v0);
        float denom = 1.0f + ex;
        float p0 = 1.0f / denom, p1 = ex / denom;
        int s0 = atomicAdd(&cnt[e0], 1);
        int s1 = atomicAdd(&cnt[e1], 1);
        lst[e0 * NTOK + s0] = row;
        lst[e1 * NTOK + s1] = row;
        te[row * 2 + 0] = e0; te[row * 2 + 1] = e1;
        ts[row * 2 + 0] = s0; ts[row * 2 + 1] = s1;
        tp[row * 2 + 0] = p0; tp[row * 2 + 1] = p1;
    }
}

__global__ void k_offs(const int* __restrict__ cnt, int* __restrict__ offs) {
    if (threadIdx.x == 0 && blockIdx.x == 0) {
        int a = 0;
        #pragma unroll
        for (int e = 0; e < E_; e++) { offs[e] = a; a += cnt[e]; }
    }
}

// ---------------- bf16 MFMA 128x128 GEMM core (BK=32) ----------------
#define LDK 48
__device__ __forceinline__ void mfma_core(const unsigned short* __restrict__ A, int strideA,
        const int* __restrict__ gather, int m0, int M,
        const unsigned short* __restrict__ Bt, int n0, int K, f32x4 acc[4][4]) {
    __shared__ unsigned short As[128 * LDK];
    __shared__ unsigned short Bs[128 * LDK];
    int t = threadIdx.x;
    int lane = t & 63, w = t >> 6;
    int wm = (w >> 1) * 64, wn = (w & 1) * 64;
    int r = t >> 1, kc = (t & 1) * 16;
    int arow;
    if (gather) { int mm = m0 + r; arow = gather[mm < M ? mm : 0]; }
    else arow = m0 + r;
    const unsigned short* Ap = A + (size_t)arow * strideA + kc;
    const unsigned short* Bp = Bt + (size_t)(n0 + r) * K + kc;
    int c15 = lane & 15, fk = (lane >> 4) * 8;
    unsigned short* AsW = &As[r * LDK + kc];
    unsigned short* BsW = &Bs[r * LDK + kc];
    for (int k0 = 0; k0 < K; k0 += 32) {
        uint4 a0 = *(const uint4*)(Ap + k0);
        uint4 a1 = *(const uint4*)(Ap + k0 + 8);
        uint4 b0 = *(const uint4*)(Bp + k0);
        uint4 b1 = *(const uint4*)(Bp + k0 + 8);
        __syncthreads();
        *(uint4*)(AsW) = a0; *(uint4*)(AsW + 8) = a1;
        *(uint4*)(BsW) = b0; *(uint4*)(BsW + 8) = b1;
        __syncthreads();
        bf16x8 af[4], bfr[4];
        #pragma unroll
        for (int i = 0; i < 4; i++) {
            af[i]  = *(const bf16x8*)(&As[(wm + c15 + i * 16) * LDK + fk]);
            bfr[i] = *(const bf16x8*)(&Bs[(wn + c15 + i * 16) * LDK + fk]);
        }
        #pragma unroll
        for (int mi = 0; mi < 4; mi++)
            #pragma unroll
            for (int ni = 0; ni < 4; ni++)
                acc[mi][ni] = __builtin_amdgcn_mfma_f32_16x16x32_bf16(af[mi], bfr[ni], acc[mi][ni], 0, 0, 0);
    }
}

// ---------------- MoE GEMM1: hid = gelu(h2[tok] @ we1[e] + be1[e]) ----------------
__global__ __launch_bounds__(256, 2) void k_moe1(const unsigned short* __restrict__ h2,
        const unsigned short* __restrict__ w1t, const float* __restrict__ be1,
        const int* __restrict__ cnt, const int* __restrict__ offs, const int* __restrict__ lst,
        unsigned short* __restrict__ hid) {
    int e = blockIdx.z;
    int M = cnt[e];
    int m0 = blockIdx.y * 128;
    if (m0 >= M) return;
    int n0 = blockIdx.x * 128;
    f32x4 acc[4][4];
    #pragma unroll
    for (int i = 0; i < 4; i++)
        #pragma unroll
        for (int j = 0; j < 4; j++) { acc[i][j].x = 0.f; acc[i][j].y = 0.f; acc[i][j].z = 0.f; acc[i][j].w = 0.f; }
    mfma_core(h2, D_, lst + e * NTOK, m0, M, w1t + (size_t)e * F_ * D_, n0, D_, acc);
    int lane = threadIdx.x & 63, w = threadIdx.x >> 6;
    int wm = (w >> 1) * 64, wn = (w & 1) * 64;
    int base = offs[e];
    const float* b1 = be1 + (size_t)e * F_;
    int c15 = lane & 15, quad = lane >> 4;
    #pragma unroll
    for (int mi = 0; mi < 4; mi++) {
        #pragma unroll
        for (int rr = 0; rr < 4; rr++) {
            int row = m0 + wm + mi * 16 + quad * 4 + rr;
            if (row < M) {
                size_t rb = (size_t)(base + row) * F_;
                #pragma unroll
                for (int ni = 0; ni < 4; ni++) {
                    int col = n0 + wn + ni * 16 + c15;
                    float xv = acc[mi][ni][rr] + b1[col];
                    float ge = 0.5f * xv * (1.0f + erff(xv * 0.70710678118654752f));
                    hid[rb + col] = f2bf(ge);
                }
            }
        }
    }
}

// ---------------- MoE GEMM2: eo = hid @ we2[e] + be2[e] ----------------
__global__ __launch_bounds__(256, 2) void k_moe2(const unsigned short* __restrict__ hid,
        const unsigned short* __restrict__ w2t, const float* __restrict__ be2,
        const int* __restrict__ cnt, const int* __restrict__ offs, float* __restrict__ eo) {
    int e = blockIdx.z;
    int M = cnt[e];
    int m0 = blockIdx.y * 128;
    if (m0 >= M) return;
    int n0 = blockIdx.x * 128;
    int base = offs[e];
    f32x4 acc[4][4];
    #pragma unroll
    for (int i = 0; i < 4; i++)
        #pragma unroll
        for (int j = 0; j < 4; j++) { acc[i][j].x = 0.f; acc[i][j].y = 0.f; acc[i][j].z = 0.f; acc[i][j].w = 0.f; }
    mfma_core(hid + (size_t)base * F_, F_, nullptr, m0, M, w2t + (size_t)e * D_ * F_, n0, F_, acc);
    int lane = threadIdx.x & 63, w = threadIdx.x >> 6;
    int wm = (w >> 1) * 64, wn = (w & 1) * 64;
    const float* b2 = be2 + (size_t)e * D_;
    int c15 = lane & 15, quad = lane >> 4;
    #pragma unroll
    for (int mi = 0; mi < 4; mi++) {
        #pragma unroll
        for (int rr = 0; rr < 4; rr++) {
            int row = m0 + wm + mi * 16 + quad * 4 + rr;
            if (row < M) {
                size_t rb = (size_t)(base + row) * D_;
                #pragma unroll
                for (int ni = 0; ni < 4; ni++) {
                    int col = n0 + wn + ni * 16 + c15;
                    eo[rb + col] = acc[mi][ni][rr] + b2[col];
                }
            }
        }
    }
}

// ---------------- final: mix top-2, post-LN, residual ----------------
__global__ void k_final(const float* __restrict__ x2, const float* __restrict__ eo,
        const int* __restrict__ te, const int* __restrict__ ts, const float* __restrict__ tp,
        const int* __restrict__ offs, const float* __restrict__ png, const float* __restrict__ pnb,
        float* __restrict__ out) {
    int row = blockIdx.x, t = threadIdx.x;
    int e0 = te[row * 2], e1 = te[row * 2 + 1];
    size_t g0 = (size_t)(offs[e0] + ts[row * 2]);
    size_t g1 = (size_t)(offs[e1] + ts[row * 2 + 1]);
    float p0 = tp[row * 2], p1 = tp[row * 2 + 1];
    f32x4 a = *(const f32x4*)(eo + g0 * D_ + t * 4);
    f32x4 b = *(const f32x4*)(eo + g1 * D_ + t * 4);
    f32x4 mo = p0 * a + p1 * b;
    float s = mo.x + mo.y + mo.z + mo.w;
    float sq = mo.x * mo.x + mo.y * mo.y + mo.z * mo.z + mo.w * mo.w;
    blockreduce2(s, sq);
    float mean = s * (1.0f / D_), var = sq * (1.0f / D_) - mean * mean;
    float inv = rsqrtf(var + EPS_);
    f32x4 gv = *(const f32x4*)(png + t * 4);
    f32x4 bv = *(const f32x4*)(pnb + t * 4);
    f32x4 xv = *(const f32x4*)(x2 + (size_t)row * D_ + t * 4);
    f32x4 o;
    o.x = xv.x + (mo.x - mean) * inv * gv.x + bv.x;
    o.y = xv.y + (mo.y - mean) * inv * gv.y + bv.y;
    o.z = xv.z + (mo.z - mean) * inv * gv.z + bv.z;
    o.w = xv.w + (mo.w - mean) * inv * gv.w + bv.w;
    *(f32x4*)(out + (size_t)row * D_ + t * 4) = o;
}

extern "C" void kernel_launch(void* const* d_in, const int* in_sizes, int n_in,
                              void* d_out, int out_size, void* d_ws, size_t ws_size,
                              hipStream_t stream) {
    (void)in_sizes; (void)n_in; (void)out_size; (void)ws_size;
    const float* x    = (const float*)d_in[0];
    const float* ln1g = (const float*)d_in[2];
    const float* ln1b = (const float*)d_in[3];
    const float* wq   = (const float*)d_in[4];
    const float* bq   = (const float*)d_in[5];
    const float* wk   = (const float*)d_in[6];
    const float* bk   = (const float*)d_in[7];
    const float* wv   = (const float*)d_in[8];
    const float* bv   = (const float*)d_in[9];
    const float* wo   = (const float*)d_in[10];
    const float* bo   = (const float*)d_in[11];
    const float* ln2g = (const float*)d_in[12];
    const float* ln2b = (const float*)d_in[13];
    const float* gw   = (const float*)d_in[14];
    const float* gb   = (const float*)d_in[15];
    const float* we1  = (const float*)d_in[16];
    const float* be1  = (const float*)d_in[17];
    const float* we2  = (const float*)d_in[18];
    const float* be2  = (const float*)d_in[19];
    const float* png  = (const float*)d_in[20];
    const float* pnb  = (const float*)d_in[21];
    float* out = (float*)d_out;

    char* ws = (char*)d_ws;
    size_t off = 0;
    auto alloc = [&](size_t bytes) { void* p = ws + off; off += (bytes + 255) & ~(size_t)255; return p; };
    float* h1  = (float*)alloc((size_t)NTOK * D_ * 4);
    float* Qp  = (float*)alloc((size_t)NTOK * D_ * 4);
    float* Kp  = (float*)alloc((size_t)NTOK * D_ * 4);
    float* Vp  = (float*)alloc((size_t)NTOK * D_ * 4);
    float* att = (float*)alloc((size_t)NTOK * D_ * 4);
    float* x2  = (float*)alloc((size_t)NTOK * D_ * 4);
    unsigned short* h2  = (unsigned short*)alloc((size_t)NTOK * D_ * 2);
    unsigned short* w1t = (unsigned short*)alloc((size_t)E_ * D_ * F_ * 2);
    unsigned short* w2t = (unsigned short*)alloc((size_t)E_ * D_ * F_ * 2);
    unsigned short* hid = (unsigned short*)alloc((size_t)(2 * NTOK + 128) * F_ * 2);
    float* eo  = (float*)alloc((size_t)(2 * NTOK) * D_ * 4);
    float* opart = (float*)alloc((size_t)64 * NSLOT * 64 * 64 * 4);   // 41.9 MB
    float* mlpart= (float*)alloc((size_t)64 * NSLOT * 128 * 4);       // 1.3 MB
    int* cnt   = (int*)alloc(256);
    int* offs  = (int*)alloc(256);
    int* lst   = (int*)alloc((size_t)E_ * NTOK * 4);
    int* te    = (int*)alloc((size_t)NTOK * 2 * 4);
    int* ts    = (int*)alloc((size_t)NTOK * 2 * 4);
    float* tp  = (float*)alloc((size_t)NTOK * 2 * 4);

    k_zero<<<dim3(1), dim3(64), 0, stream>>>(cnt);
    k_tconv<<<dim3(F_ / 32, D_ / 32, E_), dim3(256), 0, stream>>>(we1, w1t, D_, F_);
    k_tconv<<<dim3(D_ / 32, F_ / 32, E_), dim3(256), 0, stream>>>(we2, w2t, F_, D_);
    k_ln1<<<dim3(NTOK), dim3(256), 0, stream>>>(x, ln1g, ln1b, h1);
    k_qkv<<<dim3(D_ / 128, NTOK / 128, 3), dim3(256), 0, stream>>>(h1, wq, wk, wv, bq, bk, bv, Qp, Kp, Vp);
    k_attn1<<<dim3(4, T_ / 64, B_ * H_), dim3(256), 0, stream>>>(Qp, Kp, Vp, opart, mlpart);
    k_attn2<<<dim3(T_ / 64, B_ * H_), dim3(256), 0, stream>>>(opart, mlpart, att);
    k_proj<<<dim3(D_ / 128, NTOK / 128, 1), dim3(256), 0, stream>>>(att, wo, bo, x, x2);
    k_ln2_gate<<<dim3(NTOK), dim3(256), 0, stream>>>(x2, ln2g, ln2b, gw, gb, h2, cnt, lst, te, ts, tp);
    k_offs<<<dim3(1), dim3(64), 0, stream>>>(cnt, offs);
    k_moe1<<<dim3(F_ / 128, NTOK / 128, E_), dim3(256), 0, stream>>>(h2, w1t, be1, cnt, offs, lst, hid);
    k_moe2<<<dim3(D_ / 128, NTOK / 128, E_), dim3(256), 0, stream>>>(hid, w2t, be2, cnt, offs, eo);
    k_final<<<dim3(NTOK), dim3(256), 0, stream>>>(x2, eo, te, ts, tp, offs, png, pnb, out);
}

// Round 4
// 1568.919 us; speedup vs baseline: 1.1393x; 1.1393x over previous
//
#include <hip/hip_runtime.h>
#include <hip/hip_bf16.h>
#include <math.h>

#define B_ 4
#define T_ 1024
#define D_ 1024
#define H_ 16
#define DH_ 64
#define F_ 4096
#define E_ 8
#define NTOK 4096
#define EPS_ 1e-5f

typedef float f32x4 __attribute__((ext_vector_type(4)));
typedef __bf16 bf16x8 __attribute__((ext_vector_type(8)));

__device__ __forceinline__ unsigned short f2bf(float f) {
    unsigned u = __float_as_uint(f);
    u = u + 0x7fffu + ((u >> 16) & 1u);   // round-to-nearest-even
    return (unsigned short)(u >> 16);
}

__device__ __forceinline__ void blockreduce2(float& s, float& sq) {
    #pragma unroll
    for (int o = 32; o > 0; o >>= 1) { s += __shfl_xor(s, o); sq += __shfl_xor(sq, o); }
    __shared__ float ls[4], lq[4];
    int w = threadIdx.x >> 6;
    if ((threadIdx.x & 63) == 0) { ls[w] = s; lq[w] = sq; }
    __syncthreads();
    s = ls[0] + ls[1] + ls[2] + ls[3];
    sq = lq[0] + lq[1] + lq[2] + lq[3];
}

// ---------------- zero routing counters ----------------
__global__ void k_zero(int* __restrict__ cnt) {
    if (threadIdx.x < E_) cnt[threadIdx.x] = 0;
}

// ------------- transpose fp32[e][R][C] -> bf16[e][C][R] -------------
__global__ void k_tconv(const float* __restrict__ in, unsigned short* __restrict__ out,
                        int R, int C) {
    __shared__ float tile[32][33];
    int e = blockIdx.z;
    const float* ine = in + (size_t)e * R * C;
    unsigned short* oute = out + (size_t)e * R * C;
    int tx = threadIdx.x & 31, ty = threadIdx.x >> 5;   // 32 x 8
    int c0 = blockIdx.x * 32, r0 = blockIdx.y * 32;
    #pragma unroll
    for (int j = 0; j < 32; j += 8)
        tile[ty + j][tx] = ine[(size_t)(r0 + ty + j) * C + c0 + tx];
    __syncthreads();
    #pragma unroll
    for (int j = 0; j < 32; j += 8)
        oute[(size_t)(c0 + ty + j) * R + r0 + tx] = f2bf(tile[tx][ty + j]);
}

// ---------------- LayerNorm (fp32 out) ----------------
__global__ void k_ln1(const float* __restrict__ x, const float* __restrict__ g,
                      const float* __restrict__ b, float* __restrict__ h) {
    int row = blockIdx.x, t = threadIdx.x;
    f32x4 v = *(const f32x4*)(x + (size_t)row * D_ + t * 4);
    float s = v.x + v.y + v.z + v.w;
    float sq = v.x * v.x + v.y * v.y + v.z * v.z + v.w * v.w;
    blockreduce2(s, sq);
    float mean = s * (1.0f / D_);
    float var = sq * (1.0f / D_) - mean * mean;
    float inv = rsqrtf(var + EPS_);
    f32x4 gv = *(const f32x4*)(g + t * 4);
    f32x4 bv = *(const f32x4*)(b + t * 4);
    f32x4 o;
    o.x = (v.x - mean) * inv * gv.x + bv.x;
    o.y = (v.y - mean) * inv * gv.y + bv.y;
    o.z = (v.z - mean) * inv * gv.z + bv.z;
    o.w = (v.w - mean) * inv * gv.w + bv.w;
    *(f32x4*)(h + (size_t)row * D_ + t * 4) = o;
}

// ---------------- fp32 128x128 GEMM core (BK=8, 8x8 per thread) ----------------
#define FBK 8
__device__ __forceinline__ void gemm128_f32(const float* __restrict__ A,
        const float* __restrict__ W, int m0, int n0, int K, int N, float acc[8][8]) {
    __shared__ float As[FBK][128];
    __shared__ float Bs[FBK][128];
    int t = threadIdx.x;
    int tx = t & 15, ty = t >> 4;
    int arow = t >> 1, akc = (t & 1) * 4;
    int bk = t >> 5, bcol = (t & 31) * 4;
    const float* Ap = A + (size_t)(m0 + arow) * K + akc;
    const float* Wp = W + (size_t)bk * N + n0 + bcol;
    for (int k0 = 0; k0 < K; k0 += FBK) {
        f32x4 av = *(const f32x4*)(Ap + k0);
        f32x4 bv = *(const f32x4*)(Wp + (size_t)k0 * N);
        __syncthreads();
        As[akc + 0][arow] = av.x; As[akc + 1][arow] = av.y;
        As[akc + 2][arow] = av.z; As[akc + 3][arow] = av.w;
        *(f32x4*)(&Bs[bk][bcol]) = bv;
        __syncthreads();
        #pragma unroll
        for (int kk = 0; kk < FBK; kk++) {
            f32x4 a0 = *(const f32x4*)(&As[kk][ty * 8]);
            f32x4 a1 = *(const f32x4*)(&As[kk][ty * 8 + 4]);
            f32x4 b0 = *(const f32x4*)(&Bs[kk][tx * 8]);
            f32x4 b1 = *(const f32x4*)(&Bs[kk][tx * 8 + 4]);
            float aa[8] = {a0.x, a0.y, a0.z, a0.w, a1.x, a1.y, a1.z, a1.w};
            float bb[8] = {b0.x, b0.y, b0.z, b0.w, b1.x, b1.y, b1.z, b1.w};
            #pragma unroll
            for (int i = 0; i < 8; i++)
                #pragma unroll
                for (int j = 0; j < 8; j++)
                    acc[i][j] = fmaf(aa[i], bb[j], acc[i][j]);
        }
    }
}

// ---------------- QKV projection (fp32), scatter to [B,H,T,DH] ----------------
__global__ __launch_bounds__(256, 2) void k_qkv(const float* __restrict__ h1,
        const float* __restrict__ wq, const float* __restrict__ wk, const float* __restrict__ wv,
        const float* __restrict__ bq, const float* __restrict__ bk, const float* __restrict__ bv,
        float* __restrict__ Q, float* __restrict__ Kk, float* __restrict__ V) {
    int which = blockIdx.z;
    const float* W = (which == 0) ? wq : ((which == 1) ? wk : wv);
    const float* bias = (which == 0) ? bq : ((which == 1) ? bk : bv);
    float* O = (which == 0) ? Q : ((which == 1) ? Kk : V);
    float acc[8][8];
    #pragma unroll
    for (int i = 0; i < 8; i++)
        #pragma unroll
        for (int j = 0; j < 8; j++) acc[i][j] = 0.f;
    int m0 = blockIdx.y * 128, n0 = blockIdx.x * 128;
    gemm128_f32(h1, W, m0, n0, D_, D_, acc);
    int t = threadIdx.x, tx = t & 15, ty = t >> 4;
    #pragma unroll
    for (int i = 0; i < 8; i++) {
        int m = m0 + ty * 8 + i;
        int bidx = m >> 10, tt = m & 1023;
        #pragma unroll
        for (int jj = 0; jj < 8; jj += 4) {
            int n = n0 + tx * 8 + jj;
            int hh = n >> 6, d = n & 63;
            f32x4 o;
            o.x = acc[i][jj + 0] + bias[n + 0];
            o.y = acc[i][jj + 1] + bias[n + 1];
            o.z = acc[i][jj + 2] + bias[n + 2];
            o.w = acc[i][jj + 3] + bias[n + 3];
            *(f32x4*)(O + (((size_t)bidx * H_ + hh) * T_ + tt) * DH_ + d) = o;
        }
    }
}

// ---------------- output projection + residual (fp32) ----------------
__global__ __launch_bounds__(256, 2) void k_proj(const float* __restrict__ att,
        const float* __restrict__ wo, const float* __restrict__ bo,
        const float* __restrict__ x, float* __restrict__ x2) {
    float acc[8][8];
    #pragma unroll
    for (int i = 0; i < 8; i++)
        #pragma unroll
        for (int j = 0; j < 8; j++) acc[i][j] = 0.f;
    int m0 = blockIdx.y * 128, n0 = blockIdx.x * 128;
    gemm128_f32(att, wo, m0, n0, D_, D_, acc);
    int t = threadIdx.x, tx = t & 15, ty = t >> 4;
    #pragma unroll
    for (int i = 0; i < 8; i++) {
        int m = m0 + ty * 8 + i;
        #pragma unroll
        for (int jj = 0; jj < 8; jj += 4) {
            int n = n0 + tx * 8 + jj;
            f32x4 xv = *(const f32x4*)(x + (size_t)m * D_ + n);
            f32x4 o;
            o.x = acc[i][jj + 0] + bo[n + 0] + xv.x;
            o.y = acc[i][jj + 1] + bo[n + 1] + xv.y;
            o.z = acc[i][jj + 2] + bo[n + 2] + xv.z;
            o.w = acc[i][jj + 3] + bo[n + 3] + xv.w;
            *(f32x4*)(x2 + (size_t)m * D_ + n) = o;
        }
    }
}

// ---------------- flash attention pass 1: register-tiled split-K ----------------
// grid (sp=4, qt=16, bh=64). Block = 256 thr (16x16); block owns <=256 keys of
// one 64-query tile, processed in 64-key tiles by ALL 4 waves together.
// Thread (tx,ty) owns scores[4q x 4k] and out[4q x 4d]; FMA:LDS-read ~16:1.
#define NSLOT 40
__device__ __forceinline__ int slot_base(int qt) {
    const int base[16] = {0,1,2,3,4,6,8,10,12,15,18,21,24,28,32,36};
    return base[qt];
}
#define LQ 68
__global__ __launch_bounds__(256) void k_attn1(const float* __restrict__ Q,
        const float* __restrict__ K, const float* __restrict__ V,
        float* __restrict__ opart, float* __restrict__ mlpart) {
    __shared__ float Qs[64 * LQ];   // [d][q]
    __shared__ float Ks[64 * LQ];   // [d][k]
    __shared__ float Ps[64 * LQ];   // [q][k]
    __shared__ float Vs[64 * 64];   // [k][d] flat
    int sp = blockIdx.x, qt = blockIdx.y, bh = blockIdx.z;
    int lim = (qt + 1) * 64;
    int s0 = sp * 256;
    if (s0 >= lim) return;
    int ntile = min(4, (lim - s0) >> 6);
    int t = threadIdx.x;
    int tx = t & 15, ty = t >> 4;
    const float* Qb = Q + (size_t)bh * T_ * DH_;
    const float* Kb = K + (size_t)bh * T_ * DH_;
    const float* Vb = V + (size_t)bh * T_ * DH_;
    // ---- stage Q^T once: thread loads Q[qt*64 + (t&63)][db..db+15] ----
    {
        int qq = t & 63, db = (t >> 6) * 16;
        const float* src = Qb + (size_t)(qt * 64 + qq) * DH_ + db;
        f32x4 v0 = *(const f32x4*)(src + 0);
        f32x4 v1 = *(const f32x4*)(src + 4);
        f32x4 v2 = *(const f32x4*)(src + 8);
        f32x4 v3 = *(const f32x4*)(src + 12);
        #pragma unroll
        for (int i = 0; i < 4; i++) Qs[(db + 0 + i) * LQ + qq] = v0[i];
        #pragma unroll
        for (int i = 0; i < 4; i++) Qs[(db + 4 + i) * LQ + qq] = v1[i];
        #pragma unroll
        for (int i = 0; i < 4; i++) Qs[(db + 8 + i) * LQ + qq] = v2[i];
        #pragma unroll
        for (int i = 0; i < 4; i++) Qs[(db + 12 + i) * LQ + qq] = v3[i];
    }
    f32x4 o[4];
    #pragma unroll
    for (int i = 0; i < 4; i++) { o[i].x = 0.f; o[i].y = 0.f; o[i].z = 0.f; o[i].w = 0.f; }
    float m[4] = {-1e30f, -1e30f, -1e30f, -1e30f};
    float l[4] = {0.f, 0.f, 0.f, 0.f};
    int qglob = qt * 64 + ty * 4;     // thread's first q row
    for (int kt = 0; kt < ntile; kt++) {
        int kbase = s0 + kt * 64;
        __syncthreads();               // protect Ks/Vs from previous-iter readers
        // stage K^T (transpose via b32 scatter, 2-way-free banks)
        {
            int kk = t & 63, db = (t >> 6) * 16;
            const float* src = Kb + (size_t)(kbase + kk) * DH_ + db;
            f32x4 v0 = *(const f32x4*)(src + 0);
            f32x4 v1 = *(const f32x4*)(src + 4);
            f32x4 v2 = *(const f32x4*)(src + 8);
            f32x4 v3 = *(const f32x4*)(src + 12);
            #pragma unroll
            for (int i = 0; i < 4; i++) Ks[(db + 0 + i) * LQ + kk] = v0[i];
            #pragma unroll
            for (int i = 0; i < 4; i++) Ks[(db + 4 + i) * LQ + kk] = v1[i];
            #pragma unroll
            for (int i = 0; i < 4; i++) Ks[(db + 8 + i) * LQ + kk] = v2[i];
            #pragma unroll
            for (int i = 0; i < 4; i++) Ks[(db + 12 + i) * LQ + kk] = v3[i];
            // stage V flat (fully coalesced, conflict-free)
            const float* vsrc = Vb + (size_t)kbase * DH_;
            #pragma unroll
            for (int i = 0; i < 4; i++)
                *(f32x4*)(Vs + i * 1024 + t * 4) = *(const f32x4*)(vsrc + i * 1024 + t * 4);
        }
        __syncthreads();
        // ---- score GEMM: s[4q][4k] over d ----
        f32x4 sa[4];
        #pragma unroll
        for (int i = 0; i < 4; i++) { sa[i].x = 0.f; sa[i].y = 0.f; sa[i].z = 0.f; sa[i].w = 0.f; }
        #pragma unroll 4
        for (int d = 0; d < 64; d++) {
            f32x4 qv = *(const f32x4*)(Qs + d * LQ + ty * 4);   // broadcast x16
            f32x4 kv = *(const f32x4*)(Ks + d * LQ + tx * 4);
            sa[0] += qv.x * kv;
            sa[1] += qv.y * kv;
            sa[2] += qv.z * kv;
            sa[3] += qv.w * kv;
        }
        // ---- mask + online softmax ----
        int kcol = kbase + tx * 4;
        float alpha[4];
        #pragma unroll
        for (int i = 0; i < 4; i++) {
            int qr = qglob + i;
            sa[i] *= 0.125f;
            sa[i].x = (kcol + 0 <= qr) ? sa[i].x : -1e30f;
            sa[i].y = (kcol + 1 <= qr) ? sa[i].y : -1e30f;
            sa[i].z = (kcol + 2 <= qr) ? sa[i].z : -1e30f;
            sa[i].w = (kcol + 3 <= qr) ? sa[i].w : -1e30f;
            float rm = fmaxf(fmaxf(sa[i].x, sa[i].y), fmaxf(sa[i].z, sa[i].w));
            rm = fmaxf(rm, __shfl_xor(rm, 1));
            rm = fmaxf(rm, __shfl_xor(rm, 2));
            rm = fmaxf(rm, __shfl_xor(rm, 4));
            rm = fmaxf(rm, __shfl_xor(rm, 8));
            float mnew = fmaxf(m[i], rm);
            alpha[i] = __expf(m[i] - mnew);
            m[i] = mnew;
            // p = exp(s - mnew), guarded for all-masked rows (mnew = -1e30)
            sa[i].x = (sa[i].x > -1e29f) ? __expf(sa[i].x - mnew) : 0.f;
            sa[i].y = (sa[i].y > -1e29f) ? __expf(sa[i].y - mnew) : 0.f;
            sa[i].z = (sa[i].z > -1e29f) ? __expf(sa[i].z - mnew) : 0.f;
            sa[i].w = (sa[i].w > -1e29f) ? __expf(sa[i].w - mnew) : 0.f;
            float rs = sa[i].x + sa[i].y + sa[i].z + sa[i].w;
            rs += __shfl_xor(rs, 1);
            rs += __shfl_xor(rs, 2);
            rs += __shfl_xor(rs, 4);
            rs += __shfl_xor(rs, 8);
            l[i] = l[i] * alpha[i] + rs;
            o[i] *= alpha[i];
            // write P row to LDS [q][k]
            *(f32x4*)(Ps + (ty * 4 + i) * LQ + tx * 4) = sa[i];
        }
        __syncthreads();
        // ---- PV GEMM: o[4q][4d] over k ----
        const float* p0 = Ps + (ty * 4 + 0) * LQ;
        const float* p1 = Ps + (ty * 4 + 1) * LQ;
        const float* p2 = Ps + (ty * 4 + 2) * LQ;
        const float* p3 = Ps + (ty * 4 + 3) * LQ;
        #pragma unroll 4
        for (int k = 0; k < 64; k++) {
            f32x4 vv = *(const f32x4*)(Vs + k * 64 + tx * 4);
            o[0] += p0[k] * vv;
            o[1] += p1[k] * vv;
            o[2] += p2[k] * vv;
            o[3] += p3[k] * vv;
        }
    }
    // ---- write unnormalized partial + (m,l) ----
    int slot = bh * NSLOT + slot_base(qt) + sp;
    float* dst = opart + ((size_t)slot * 64 + ty * 4) * 64 + tx * 4;
    #pragma unroll
    for (int i = 0; i < 4; i++)
        *(f32x4*)(dst + (size_t)i * 64) = o[i];
    if (tx == 0) {
        #pragma unroll
        for (int i = 0; i < 4; i++) {
            mlpart[slot * 128 + (ty * 4 + i) * 2 + 0] = m[i];
            mlpart[slot * 128 + (ty * 4 + i) * 2 + 1] = l[i];
        }
    }
}

// ---------------- flash attention pass 2: merge <=4 partials, normalize ----------------
__global__ void k_attn2(const float* __restrict__ opart, const float* __restrict__ mlpart,
                        float* __restrict__ O) {
    int qt = blockIdx.x, bh = blockIdx.y;
    int b = bh >> 4, h = bh & 15;
    int nsp = (qt >> 2) + 1;
    int slot0 = bh * NSLOT + slot_base(qt);
    int tid = threadIdx.x;
    int q = tid >> 2, d0 = (tid & 3) * 16;
    float ms[4], ls[4];
    float mx = -1e30f;
    for (int s = 0; s < nsp; s++) {
        ms[s] = mlpart[(slot0 + s) * 128 + q * 2 + 0];
        ls[s] = mlpart[(slot0 + s) * 128 + q * 2 + 1];
        mx = fmaxf(mx, ms[s]);
    }
    float den = 0.f;
    f32x4 num[4];
    #pragma unroll
    for (int i = 0; i < 4; i++) { num[i].x = 0.f; num[i].y = 0.f; num[i].z = 0.f; num[i].w = 0.f; }
    for (int s = 0; s < nsp; s++) {
        float sc = __expf(ms[s] - mx);
        den += ls[s] * sc;
        const float* src = opart + ((size_t)(slot0 + s) * 64 + q) * 64 + d0;
        #pragma unroll
        for (int i = 0; i < 4; i++) num[i] += sc * *(const f32x4*)(src + i * 4);
    }
    float inv = 1.0f / den;
    float* Or = O + ((size_t)(b * T_ + qt * 64 + q)) * D_ + h * DH_ + d0;
    #pragma unroll
    for (int i = 0; i < 4; i++) *(f32x4*)(Or + i * 4) = num[i] * inv;
}

// ---------------- LN2 + gate (fp32 logits, top-2, routing) ----------------
__global__ void k_ln2_gate(const float* __restrict__ x2, const float* __restrict__ g,
        const float* __restrict__ bb, const float* __restrict__ gw, const float* __restrict__ gb,
        unsigned short* __restrict__ h2, int* __restrict__ cnt, int* __restrict__ lst,
        int* __restrict__ te, int* __restrict__ ts, float* __restrict__ tp) {
    int row = blockIdx.x, t = threadIdx.x;
    f32x4 v = *(const f32x4*)(x2 + (size_t)row * D_ + t * 4);
    float s = v.x + v.y + v.z + v.w;
    float sq = v.x * v.x + v.y * v.y + v.z * v.z + v.w * v.w;
    blockreduce2(s, sq);
    float mean = s * (1.0f / D_), var = sq * (1.0f / D_) - mean * mean;
    float inv = rsqrtf(var + EPS_);
    f32x4 gv = *(const f32x4*)(g + t * 4);
    f32x4 bv = *(const f32x4*)(bb + t * 4);
    float hv[4];
    #pragma unroll
    for (int i = 0; i < 4; i++) hv[i] = (v[i] - mean) * inv * gv[i] + bv[i];
    ushort4 hb;
    hb.x = f2bf(hv[0]); hb.y = f2bf(hv[1]); hb.z = f2bf(hv[2]); hb.w = f2bf(hv[3]);
    *(ushort4*)(&h2[(size_t)row * D_ + t * 4]) = hb;
    float lg[8];
    #pragma unroll
    for (int e2 = 0; e2 < 8; e2++) lg[e2] = 0.f;
    #pragma unroll
    for (int i = 0; i < 4; i++) {
        const float* gr = gw + (size_t)(t * 4 + i) * E_;
        f32x4 g0 = *(const f32x4*)(gr);
        f32x4 g1 = *(const f32x4*)(gr + 4);
        lg[0] = fmaf(hv[i], g0.x, lg[0]); lg[1] = fmaf(hv[i], g0.y, lg[1]);
        lg[2] = fmaf(hv[i], g0.z, lg[2]); lg[3] = fmaf(hv[i], g0.w, lg[3]);
        lg[4] = fmaf(hv[i], g1.x, lg[4]); lg[5] = fmaf(hv[i], g1.y, lg[5]);
        lg[6] = fmaf(hv[i], g1.z, lg[6]); lg[7] = fmaf(hv[i], g1.w, lg[7]);
    }
    #pragma unroll
    for (int o = 32; o > 0; o >>= 1) {
        #pragma unroll
        for (int e2 = 0; e2 < 8; e2++) lg[e2] += __shfl_xor(lg[e2], o);
    }
    __shared__ float lred[4][8];
    int w = t >> 6;
    if ((t & 63) == 0) {
        #pragma unroll
        for (int e2 = 0; e2 < 8; e2++) lred[w][e2] = lg[e2];
    }
    __syncthreads();
    if (t == 0) {
        float L[8];
        #pragma unroll
        for (int e2 = 0; e2 < 8; e2++)
            L[e2] = (lred[0][e2] + lred[1][e2] + lred[2][e2] + lred[3][e2] + gb[e2]) / 0.9f;
        int e0 = 0, e1 = -1; float v0 = L[0], v1 = -3e38f;
        #pragma unroll
        for (int e2 = 1; e2 < 8; e2++) {
            float xv = L[e2];
            if (xv > v0)      { v1 = v0; e1 = e0; v0 = xv; e0 = e2; }
            else if (xv > v1) { v1 = xv; e1 = e2; }
        }
        float ex = __expf(v1 - v0);
        float denom = 1.0f + ex;
        float p0 = 1.0f / denom, p1 = ex / denom;
        int s0 = atomicAdd(&cnt[e0], 1);
        int s1 = atomicAdd(&cnt[e1], 1);
        lst[e0 * NTOK + s0] = row;
        lst[e1 * NTOK + s1] = row;
        te[row * 2 + 0] = e0; te[row * 2 + 1] = e1;
        ts[row * 2 + 0] = s0; ts[row * 2 + 1] = s1;
        tp[row * 2 + 0] = p0; tp[row * 2 + 1] = p1;
    }
}

__global__ void k_offs(const int* __restrict__ cnt, int* __restrict__ offs) {
    if (threadIdx.x == 0 && blockIdx.x == 0) {
        int a = 0;
        #pragma unroll
        for (int e = 0; e < E_; e++) { offs[e] = a; a += cnt[e]; }
    }
}

// ---------------- bf16 MFMA 128x128 GEMM core (BK=32) ----------------
#define LDK 48
__device__ __forceinline__ void mfma_core(const unsigned short* __restrict__ A, int strideA,
        const int* __restrict__ gather, int m0, int M,
        const unsigned short* __restrict__ Bt, int n0, int K, f32x4 acc[4][4]) {
    __shared__ unsigned short As[128 * LDK];
    __shared__ unsigned short Bs[128 * LDK];
    int t = threadIdx.x;
    int lane = t & 63, w = t >> 6;
    int wm = (w >> 1) * 64, wn = (w & 1) * 64;
    int r = t >> 1, kc = (t & 1) * 16;
    int arow;
    if (gather) { int mm = m0 + r; arow = gather[mm < M ? mm : 0]; }
    else arow = m0 + r;
    const unsigned short* Ap = A + (size_t)arow * strideA + kc;
    const unsigned short* Bp = Bt + (size_t)(n0 + r) * K + kc;
    int c15 = lane & 15, fk = (lane >> 4) * 8;
    unsigned short* AsW = &As[r * LDK + kc];
    unsigned short* BsW = &Bs[r * LDK + kc];
    for (int k0 = 0; k0 < K; k0 += 32) {
        uint4 a0 = *(const uint4*)(Ap + k0);
        uint4 a1 = *(const uint4*)(Ap + k0 + 8);
        uint4 b0 = *(const uint4*)(Bp + k0);
        uint4 b1 = *(const uint4*)(Bp + k0 + 8);
        __syncthreads();
        *(uint4*)(AsW) = a0; *(uint4*)(AsW + 8) = a1;
        *(uint4*)(BsW) = b0; *(uint4*)(BsW + 8) = b1;
        __syncthreads();
        bf16x8 af[4], bfr[4];
        #pragma unroll
        for (int i = 0; i < 4; i++) {
            af[i]  = *(const bf16x8*)(&As[(wm + c15 + i * 16) * LDK + fk]);
            bfr[i] = *(const bf16x8*)(&Bs[(wn + c15 + i * 16) * LDK + fk]);
        }
        #pragma unroll
        for (int mi = 0; mi < 4; mi++)
            #pragma unroll
            for (int ni = 0; ni < 4; ni++)
                acc[mi][ni] = __builtin_amdgcn_mfma_f32_16x16x32_bf16(af[mi], bfr[ni], acc[mi][ni], 0, 0, 0);
    }
}

// ---------------- MoE GEMM1: hid = gelu(h2[tok] @ we1[e] + be1[e]) ----------------
__global__ __launch_bounds__(256, 2) void k_moe1(const unsigned short* __restrict__ h2,
        const unsigned short* __restrict__ w1t, const float* __restrict__ be1,
        const int* __restrict__ cnt, const int* __restrict__ offs, const int* __restrict__ lst,
        unsigned short* __restrict__ hid) {
    int e = blockIdx.z;
    int M = cnt[e];
    int m0 = blockIdx.y * 128;
    if (m0 >= M) return;
    int n0 = blockIdx.x * 128;
    f32x4 acc[4][4];
    #pragma unroll
    for (int i = 0; i < 4; i++)
        #pragma unroll
        for (int j = 0; j < 4; j++) { acc[i][j].x = 0.f; acc[i][j].y = 0.f; acc[i][j].z = 0.f; acc[i][j].w = 0.f; }
    mfma_core(h2, D_, lst + e * NTOK, m0, M, w1t + (size_t)e * F_ * D_, n0, D_, acc);
    int lane = threadIdx.x & 63, w = threadIdx.x >> 6;
    int wm = (w >> 1) * 64, wn = (w & 1) * 64;
    int base = offs[e];
    const float* b1 = be1 + (size_t)e * F_;
    int c15 = lane & 15, quad = lane >> 4;
    #pragma unroll
    for (int mi = 0; mi < 4; mi++) {
        #pragma unroll
        for (int rr = 0; rr < 4; rr++) {
            int row = m0 + wm + mi * 16 + quad * 4 + rr;
            if (row < M) {
                size_t rb = (size_t)(base + row) * F_;
                #pragma unroll
                for (int ni = 0; ni < 4; ni++) {
                    int col = n0 + wn + ni * 16 + c15;
                    float xv = acc[mi][ni][rr] + b1[col];
                    float ge = 0.5f * xv * (1.0f + erff(xv * 0.70710678118654752f));
                    hid[rb + col] = f2bf(ge);
                }
            }
        }
    }
}

// ---------------- MoE GEMM2: eo = hid @ we2[e] + be2[e] ----------------
__global__ __launch_bounds__(256, 2) void k_moe2(const unsigned short* __restrict__ hid,
        const unsigned short* __restrict__ w2t, const float* __restrict__ be2,
        const int* __restrict__ cnt, const int* __restrict__ offs, float* __restrict__ eo) {
    int e = blockIdx.z;
    int M = cnt[e];
    int m0 = blockIdx.y * 128;
    if (m0 >= M) return;
    int n0 = blockIdx.x * 128;
    int base = offs[e];
    f32x4 acc[4][4];
    #pragma unroll
    for (int i = 0; i < 4; i++)
        #pragma unroll
        for (int j = 0; j < 4; j++) { acc[i][j].x = 0.f; acc[i][j].y = 0.f; acc[i][j].z = 0.f; acc[i][j].w = 0.f; }
    mfma_core(hid + (size_t)base * F_, F_, nullptr, m0, M, w2t + (size_t)e * D_ * F_, n0, F_, acc);
    int lane = threadIdx.x & 63, w = threadIdx.x >> 6;
    int wm = (w >> 1) * 64, wn = (w & 1) * 64;
    const float* b2 = be2 + (size_t)e * D_;
    int c15 = lane & 15, quad = lane >> 4;
    #pragma unroll
    for (int mi = 0; mi < 4; mi++) {
        #pragma unroll
        for (int rr = 0; rr < 4; rr++) {
            int row = m0 + wm + mi * 16 + quad * 4 + rr;
            if (row < M) {
                size_t rb = (size_t)(base + row) * D_;
                #pragma unroll
                for (int ni = 0; ni < 4; ni++) {
                    int col = n0 + wn + ni * 16 + c15;
                    eo[rb + col] = acc[mi][ni][rr] + b2[col];
                }
            }
        }
    }
}

// ---------------- final: mix top-2, post-LN, residual ----------------
__global__ void k_final(const float* __restrict__ x2, const float* __restrict__ eo,
        const int* __restrict__ te, const int* __restrict__ ts, const float* __restrict__ tp,
        const int* __restrict__ offs, const float* __restrict__ png, const float* __restrict__ pnb,
        float* __restrict__ out) {
    int row = blockIdx.x, t = threadIdx.x;
    int e0 = te[row * 2], e1 = te[row * 2 + 1];
    size_t g0 = (size_t)(offs[e0] + ts[row * 2]);
    size_t g1 = (size_t)(offs[e1] + ts[row * 2 + 1]);
    float p0 = tp[row * 2], p1 = tp[row * 2 + 1];
    f32x4 a = *(const f32x4*)(eo + g0 * D_ + t * 4);
    f32x4 b = *(const f32x4*)(eo + g1 * D_ + t * 4);
    f32x4 mo = p0 * a + p1 * b;
    float s = mo.x + mo.y + mo.z + mo.w;
    float sq = mo.x * mo.x + mo.y * mo.y + mo.z * mo.z + mo.w * mo.w;
    blockreduce2(s, sq);
    float mean = s * (1.0f / D_), var = sq * (1.0f / D_) - mean * mean;
    float inv = rsqrtf(var + EPS_);
    f32x4 gv = *(const f32x4*)(png + t * 4);
    f32x4 bv = *(const f32x4*)(pnb + t * 4);
    f32x4 xv = *(const f32x4*)(x2 + (size_t)row * D_ + t * 4);
    f32x4 o;
    o.x = xv.x + (mo.x - mean) * inv * gv.x + bv.x;
    o.y = xv.y + (mo.y - mean) * inv * gv.y + bv.y;
    o.z = xv.z + (mo.z - mean) * inv * gv.z + bv.z;
    o.w = xv.w + (mo.w - mean) * inv * gv.w + bv.w;
    *(f32x4*)(out + (size_t)row * D_ + t * 4) = o;
}

extern "C" void kernel_launch(void* const* d_in, const int* in_sizes, int n_in,
                              void* d_out, int out_size, void* d_ws, size_t ws_size,
                              hipStream_t stream) {
    (void)in_sizes; (void)n_in; (void)out_size; (void)ws_size;
    const float* x    = (const float*)d_in[0];
    const float* ln1g = (const float*)d_in[2];
    const float* ln1b = (const float*)d_in[3];
    const float* wq   = (const float*)d_in[4];
    const float* bq   = (const float*)d_in[5];
    const float* wk   = (const float*)d_in[6];
    const float* bk   = (const float*)d_in[7];
    const float* wv   = (const float*)d_in[8];
    const float* bv   = (const float*)d_in[9];
    const float* wo   = (const float*)d_in[10];
    const float* bo   = (const float*)d_in[11];
    const float* ln2g = (const float*)d_in[12];
    const float* ln2b = (const float*)d_in[13];
    const float* gw   = (const float*)d_in[14];
    const float* gb   = (const float*)d_in[15];
    const float* we1  = (const float*)d_in[16];
    const float* be1  = (const float*)d_in[17];
    const float* we2  = (const float*)d_in[18];
    const float* be2  = (const float*)d_in[19];
    const float* png  = (const float*)d_in[20];
    const float* pnb  = (const float*)d_in[21];
    float* out = (float*)d_out;

    char* ws = (char*)d_ws;
    size_t off = 0;
    auto alloc = [&](size_t bytes) { void* p = ws + off; off += (bytes + 255) & ~(size_t)255; return p; };
    float* h1  = (float*)alloc((size_t)NTOK * D_ * 4);
    float* Qp  = (float*)alloc((size_t)NTOK * D_ * 4);
    float* Kp  = (float*)alloc((size_t)NTOK * D_ * 4);
    float* Vp  = (float*)alloc((size_t)NTOK * D_ * 4);
    float* att = (float*)alloc((size_t)NTOK * D_ * 4);
    float* x2  = (float*)alloc((size_t)NTOK * D_ * 4);
    unsigned short* h2  = (unsigned short*)alloc((size_t)NTOK * D_ * 2);
    unsigned short* w1t = (unsigned short*)alloc((size_t)E_ * D_ * F_ * 2);
    unsigned short* w2t = (unsigned short*)alloc((size_t)E_ * D_ * F_ * 2);
    unsigned short* hid = (unsigned short*)alloc((size_t)(2 * NTOK + 128) * F_ * 2);
    float* eo  = (float*)alloc((size_t)(2 * NTOK) * D_ * 4);
    float* opart = (float*)alloc((size_t)64 * NSLOT * 64 * 64 * 4);   // 41.9 MB
    float* mlpart= (float*)alloc((size_t)64 * NSLOT * 128 * 4);       // 1.3 MB
    int* cnt   = (int*)alloc(256);
    int* offs  = (int*)alloc(256);
    int* lst   = (int*)alloc((size_t)E_ * NTOK * 4);
    int* te    = (int*)alloc((size_t)NTOK * 2 * 4);
    int* ts    = (int*)alloc((size_t)NTOK * 2 * 4);
    float* tp  = (float*)alloc((size_t)NTOK * 2 * 4);

    k_zero<<<dim3(1), dim3(64), 0, stream>>>(cnt);
    k_tconv<<<dim3(F_ / 32, D_ / 32, E_), dim3(256), 0, stream>>>(we1, w1t, D_, F_);
    k_tconv<<<dim3(D_ / 32, F_ / 32, E_), dim3(256), 0, stream>>>(we2, w2t, F_, D_);
    k_ln1<<<dim3(NTOK), dim3(256), 0, stream>>>(x, ln1g, ln1b, h1);
    k_qkv<<<dim3(D_ / 128, NTOK / 128, 3), dim3(256), 0, stream>>>(h1, wq, wk, wv, bq, bk, bv, Qp, Kp, Vp);
    k_attn1<<<dim3(4, T_ / 64, B_ * H_), dim3(256), 0, stream>>>(Qp, Kp, Vp, opart, mlpart);
    k_attn2<<<dim3(T_ / 64, B_ * H_), dim3(256), 0, stream>>>(opart, mlpart, att);
    k_proj<<<dim3(D_ / 128, NTOK / 128, 1), dim3(256), 0, stream>>>(att, wo, bo, x, x2);
    k_ln2_gate<<<dim3(NTOK), dim3(256), 0, stream>>>(x2, ln2g, ln2b, gw, gb, h2, cnt, lst, te, ts, tp);
    k_offs<<<dim3(1), dim3(64), 0, stream>>>(cnt, offs);
    k_moe1<<<dim3(F_ / 128, NTOK / 128, E_), dim3(256), 0, stream>>>(h2, w1t, be1, cnt, offs, lst, hid);
    k_moe2<<<dim3(D_ / 128, NTOK / 128, E_), dim3(256), 0, stream>>>(hid, w2t, be2, cnt, offs, eo);
    k_final<<<dim3(NTOK), dim3(256), 0, stream>>>(x2, eo, te, ts, tp, offs, png, pnb, out);
}